// Round 1
// baseline (235.205 us; speedup 1.0000x reference)
//
#include <hip/hip_runtime.h>
#include <math.h>

#define DIM      64
#define N_MEM    32
#define N_ENTITY 500000
#define N_REL    32
#define N_ITEM   10000
#define HOPS     2
#define BATCH    4096
#define HIST     50

typedef float4 f4;

// ---------------------------------------------------------------------------
// Streaming pass: hdot[e] = dot(entity[e], w_h) for all 500K entities, and
// rdot[r] = dot(relation[r], w_r) for the 32 relations (appended as extra
// rows). 128 MB coalesced read ~20us at HBM BW. Removes 640K random 256B
// head-row gathers (half of stage1's L3 line traffic) and warms L3 with the
// whole entity table.
// ---------------------------------------------------------------------------
__global__ __launch_bounds__(256) void ripple_dots(
    const float* __restrict__ entity_emb,
    const float* __restrict__ relation_emb,
    const float* __restrict__ W_w,
    float* __restrict__ hdot,           // [N_ENTITY]
    float* __restrict__ rdot)           // [N_REL]
{
    const int wave = (blockIdx.x * blockDim.x + threadIdx.x) >> 6;
    const int lane = threadIdx.x & 63;
    const int g = lane >> 4;
    const int p = lane & 15;
    const int row = wave * 4 + g;       // 4 rows per wave, 16 lanes per row
    if (row >= N_ENTITY + N_REL) return;

    const f4* __restrict__ W4 = (const f4*)W_w;
    float v;
    if (row < N_ENTITY) {
        const f4 w = W4[p];                                   // w_h
        const f4 e = ((const f4*)entity_emb)[(size_t)row * 16 + p];
        v = e.x * w.x + e.y * w.y + e.z * w.z + e.w * w.w;
    } else {
        const f4 w = W4[16 + p];                              // w_r
        const f4 e = ((const f4*)relation_emb)[(size_t)(row - N_ENTITY) * 16 + p];
        v = e.x * w.x + e.y * w.y + e.z * w.z + e.w * w.w;
    }
    v += __shfl_xor(v, 1, 64);
    v += __shfl_xor(v, 2, 64);
    v += __shfl_xor(v, 4, 64);
    v += __shfl_xor(v, 8, 64);
    if (p == 0) {
        if (row < N_ENTITY) hdot[row] = v;
        else                rdot[row - N_ENTITY] = v;
    }
}

// ---------------------------------------------------------------------------
// Stage 1: one wave per (item, hop); lane = g*16+p; per wave only the 8 TAIL
// f4 row-gathers are in flight (head contribution comes from the 2MB
// L2-resident hdot table as a 4B gather; relation from rdot).
// ---------------------------------------------------------------------------
__global__ __launch_bounds__(256) void ripple_stage1(
    const float* __restrict__ W_w,
    const float* __restrict__ W_b,
    const int*   __restrict__ heads,
    const int*   __restrict__ relations,
    const int*   __restrict__ tails,
    const float* __restrict__ entity_emb,
    const float* __restrict__ hdot,
    const float* __restrict__ rdot,
    float*       __restrict__ accp)      // [N_ITEM][HOPS][DIM]
{
    const int wave = (blockIdx.x * blockDim.x + threadIdx.x) >> 6;  // = h*N_ITEM + i
    const int lane = threadIdx.x & 63;
    if (wave >= HOPS * N_ITEM) return;
    const int h = wave < N_ITEM ? 0 : 1;
    const int i = wave - h * N_ITEM;
    const int g = lane >> 4;
    const int p = lane & 15;

    const f4* __restrict__ E4 = (const f4*)entity_emb;
    const f4* __restrict__ W4 = (const f4*)W_w;

    const f4 wt = W4[32 + p];
    const float bias = W_b[0];

    const int base = wave * N_MEM + g;   // this lane's m = 4k+g

    // ---- Phase 0: indices ----
    int hi[8], ri[8], ti[8];
#pragma unroll
    for (int k = 0; k < 8; ++k) {
        hi[k] = heads[base + 4 * k];
        ri[k] = relations[base + 4 * k];
        ti[k] = tails[base + 4 * k];
    }

    // ---- Phase A: 8 tail f4 row-gathers in flight (the only L3 traffic),
    //      then small-table scalar gathers for head/relation logits ----
    f4 te[8];
#pragma unroll
    for (int k = 0; k < 8; ++k) te[k] = E4[(size_t)ti[k] * 16 + p];

    float lh[8], lr[8];
#pragma unroll
    for (int k = 0; k < 8; ++k) lh[k] = hdot[hi[k]];
#pragma unroll
    for (int k = 0; k < 8; ++k) lr[k] = rdot[ri[k]];

    float part[8];
#pragma unroll
    for (int k = 0; k < 8; ++k) {
        part[k] = te[k].x * wt.x + te[k].y * wt.y + te[k].z * wt.z + te[k].w * wt.w;
    }

    // ---- Phase B: 16-lane reduces (4 memories in parallel), sigmoid+exp ----
    float e[8];
    float se = 0.f;
#pragma unroll
    for (int k = 0; k < 8; ++k) {
        float v = part[k];
        v += __shfl_xor(v, 1, 64);
        v += __shfl_xor(v, 2, 64);
        v += __shfl_xor(v, 4, 64);
        v += __shfl_xor(v, 8, 64);
        const float logit = v + lh[k] + lr[k] + bias;
        const float sig   = 1.f / (1.f + __expf(-logit));
        const float ex    = __expf(sig);
        e[k] = ex;
        se += ex;
    }
    se += __shfl_xor(se, 16, 64);
    se += __shfl_xor(se, 32, 64);
    const float inv = 1.f / se;

    // ---- Phase C: weighted tail sum from registers ----
    f4 acc = {0.f, 0.f, 0.f, 0.f};
#pragma unroll
    for (int k = 0; k < 8; ++k) {
        const float w = e[k] * inv;
        acc.x += w * te[k].x;
        acc.y += w * te[k].y;
        acc.z += w * te[k].z;
        acc.w += w * te[k].w;
    }

    acc.x += __shfl_xor(acc.x, 16, 64);
    acc.x += __shfl_xor(acc.x, 32, 64);
    acc.y += __shfl_xor(acc.y, 16, 64);
    acc.y += __shfl_xor(acc.y, 32, 64);
    acc.z += __shfl_xor(acc.z, 16, 64);
    acc.z += __shfl_xor(acc.z, 32, 64);
    acc.w += __shfl_xor(acc.w, 16, 64);
    acc.w += __shfl_xor(acc.w, 32, 64);
    if (g == 0) ((f4*)accp)[((size_t)i * 2 + h) * 16 + p] = acc;
}

// folded[i] = entity[item_ids[i]] + accp[i][0] + accp[i][1]
__global__ __launch_bounds__(256) void ripple_fold(
    const float* __restrict__ entity_emb,
    const int*   __restrict__ item_ids,
    const float* __restrict__ accp,
    float*       __restrict__ folded)
{
    const int t = blockIdx.x * blockDim.x + threadIdx.x;
    if (t >= N_ITEM * 16) return;
    const int i = t >> 4;
    const int p = t & 15;
    const f4* __restrict__ E4 = (const f4*)entity_emb;
    const f4* __restrict__ A4 = (const f4*)accp;
    const f4 a  = A4[(size_t)i * 32 + p];
    const f4 b  = A4[(size_t)i * 32 + 16 + p];
    const f4 it = E4[(size_t)item_ids[i] * 16 + p];
    f4 r;
    r.x = it.x + a.x + b.x;
    r.y = it.y + a.y + b.y;
    r.z = it.z + a.z + b.z;
    r.w = it.w + a.w + b.w;
    ((f4*)folded)[(size_t)i * 16 + p] = r;
}

__global__ __launch_bounds__(256) void ripple_stage2(
    const float* __restrict__ entity_emb,
    const int*   __restrict__ records_idx,
    const int*   __restrict__ items,
    const float* __restrict__ folded,
    float*       __restrict__ out)
{
    const int wave = (blockIdx.x * blockDim.x + threadIdx.x) >> 6;
    const int lane = threadIdx.x & 63;
    if (wave >= BATCH) return;
    const int b = wave;
    const int g = lane >> 4;
    const int p = lane & 15;

    const f4* __restrict__ A4 = (const f4*)folded;
    const f4* __restrict__ E4 = (const f4*)entity_emb;

    const int rb = b * HIST;
    int idx[13];
    float wgt[13];
#pragma unroll
    for (int k = 0; k < 13; ++k) {
        const int j  = 4 * k + g;
        const int jc = j < HIST ? j : (HIST - 1);
        wgt[k] = j < HIST ? 1.f : 0.f;
        idx[k] = records_idx[rb + jc];
    }

    f4 user = {0.f, 0.f, 0.f, 0.f};
#pragma unroll
    for (int k = 0; k < 13; ++k) {
        const f4 r = A4[(size_t)idx[k] * 16 + p];
        user.x += wgt[k] * r.x;
        user.y += wgt[k] * r.y;
        user.z += wgt[k] * r.z;
        user.w += wgt[k] * r.w;
    }
    user.x += __shfl_xor(user.x, 16, 64);
    user.x += __shfl_xor(user.x, 32, 64);
    user.y += __shfl_xor(user.y, 16, 64);
    user.y += __shfl_xor(user.y, 32, 64);
    user.z += __shfl_xor(user.z, 16, 64);
    user.z += __shfl_xor(user.z, 32, 64);
    user.w += __shfl_xor(user.w, 16, 64);
    user.w += __shfl_xor(user.w, 32, 64);

    const f4 pair = E4[(size_t)items[b] * 16 + p];
    float dot = user.x * pair.x + user.y * pair.y + user.z * pair.z + user.w * pair.w;
    dot += __shfl_xor(dot, 1, 64);
    dot += __shfl_xor(dot, 2, 64);
    dot += __shfl_xor(dot, 4, 64);
    dot += __shfl_xor(dot, 8, 64);
    if (lane == 0) out[b] = 1.f / (1.f + __expf(-dot));
}

extern "C" void kernel_launch(void* const* d_in, const int* in_sizes, int n_in,
                              void* d_out, int out_size, void* d_ws, size_t ws_size,
                              hipStream_t stream) {
    const float* entity_emb   = (const float*)d_in[0];
    const float* relation_emb = (const float*)d_in[1];
    const float* W_w          = (const float*)d_in[2];
    const float* W_b          = (const float*)d_in[3];
    const int*   item_ids     = (const int*)d_in[4];
    const int*   heads        = (const int*)d_in[5];
    const int*   relations    = (const int*)d_in[6];
    const int*   tails        = (const int*)d_in[7];
    const int*   records_idx  = (const int*)d_in[8];
    const int*   items        = (const int*)d_in[9];
    float* out = (float*)d_out;

    float* rdot   = (float*)d_ws;                          // 128 B
    float* hdot   = rdot + N_REL;                          // 2 MB
    float* accp   = hdot + N_ENTITY;                       // 5.12 MB
    float* folded = accp + (size_t)N_ITEM * HOPS * DIM;    // 2.56 MB

    // dots: (N_ENTITY + N_REL) rows, 4 rows/wave, 4 waves/block -> 16 rows/block
    const int rowsD   = N_ENTITY + N_REL;
    const int blocksD = (rowsD + 15) / 16;
    ripple_dots<<<blocksD, 256, 0, stream>>>(entity_emb, relation_emb, W_w, hdot, rdot);

    const int waves1  = HOPS * N_ITEM;          // 20000 waves, 4 per block
    const int blocks1 = (waves1 + 3) / 4;
    ripple_stage1<<<blocks1, 256, 0, stream>>>(W_w, W_b, heads, relations, tails,
                                               entity_emb, hdot, rdot, accp);

    const int blocksF = (N_ITEM * 16 + 255) / 256;
    ripple_fold<<<blocksF, 256, 0, stream>>>(entity_emb, item_ids, accp, folded);

    const int blocks2 = (BATCH + 3) / 4;
    ripple_stage2<<<blocks2, 256, 0, stream>>>(entity_emb, records_idx, items,
                                               folded, out);
}

// Round 2
// 234.845 us; speedup vs baseline: 1.0015x; 1.0015x over previous
//
#include <hip/hip_runtime.h>
#include <math.h>

#define DIM      64
#define N_MEM    32
#define N_ENTITY 500000
#define N_REL    32
#define N_ITEM   10000
#define HOPS     2
#define BATCH    4096
#define HIST     50

typedef float4 f4;

// ---------------------------------------------------------------------------
// Streaming pass: hdot[e] = dot(entity[e], w_h) for all 500K entities, and
// rdot[r] = dot(relation[r], w_r) for the 32 relations (appended rows).
// 128 MB coalesced read ~20us at HBM BW; also warms L3 with the entity table.
// ---------------------------------------------------------------------------
__global__ __launch_bounds__(256) void ripple_dots(
    const float* __restrict__ entity_emb,
    const float* __restrict__ relation_emb,
    const float* __restrict__ W_w,
    float* __restrict__ hdot,           // [N_ENTITY]
    float* __restrict__ rdot)           // [N_REL]
{
    const int wave = (blockIdx.x * blockDim.x + threadIdx.x) >> 6;
    const int lane = threadIdx.x & 63;
    const int g = lane >> 4;
    const int p = lane & 15;
    const int row = wave * 4 + g;       // 4 rows per wave, 16 lanes per row
    if (row >= N_ENTITY + N_REL) return;

    const f4* __restrict__ W4 = (const f4*)W_w;
    float v;
    if (row < N_ENTITY) {
        const f4 w = W4[p];                                   // w_h
        const f4 e = ((const f4*)entity_emb)[(size_t)row * 16 + p];
        v = e.x * w.x + e.y * w.y + e.z * w.z + e.w * w.w;
    } else {
        const f4 w = W4[16 + p];                              // w_r
        const f4 e = ((const f4*)relation_emb)[(size_t)(row - N_ENTITY) * 16 + p];
        v = e.x * w.x + e.y * w.y + e.z * w.z + e.w * w.w;
    }
    v += __shfl_xor(v, 1, 64);
    v += __shfl_xor(v, 2, 64);
    v += __shfl_xor(v, 4, 64);
    v += __shfl_xor(v, 8, 64);
    if (p == 0) {
        if (row < N_ENTITY) hdot[row] = v;
        else                rdot[row - N_ENTITY] = v;
    }
}

// ---------------------------------------------------------------------------
// Stage 1 (TA-slot-minimal): one wave per (item, hop).
// Each distinct word is loaded by exactly ONE lane, then redistributed via
// __shfl (ds_bpermute, LDS pipe) instead of 16x-redundant per-lane gathers.
// VMEM instrs/wave: 3 idx + 1 hdot + 1 rdot + 8 tail rows + 1 store = 14
// (was 48).
// ---------------------------------------------------------------------------
__global__ __launch_bounds__(256) void ripple_stage1(
    const float* __restrict__ W_w,
    const float* __restrict__ W_b,
    const int*   __restrict__ heads,
    const int*   __restrict__ relations,
    const int*   __restrict__ tails,
    const float* __restrict__ entity_emb,
    const float* __restrict__ hdot,
    const float* __restrict__ rdot,
    float*       __restrict__ accp)      // [N_ITEM][HOPS][DIM]
{
    const int wave = (blockIdx.x * blockDim.x + threadIdx.x) >> 6;  // = h*N_ITEM + i
    const int lane = threadIdx.x & 63;
    if (wave >= HOPS * N_ITEM) return;
    const int h = wave < N_ITEM ? 0 : 1;
    const int i = wave - h * N_ITEM;
    const int g = lane >> 4;
    const int p = lane & 15;

    const f4* __restrict__ E4 = (const f4*)entity_emb;
    const f4 wt = ((const f4*)W_w)[32 + p];
    const float bias = W_b[0];

    const int base32 = wave * N_MEM;

    // ---- Phase 0: one index per lane (lanes 0..31), one gather each ----
    int   tidx = 0;
    float lh = 0.f, lr = 0.f;
    if (lane < N_MEM) {
        const int hidx = heads[base32 + lane];
        const int ridx = relations[base32 + lane];
        tidx = tails[base32 + lane];
        lh = hdot[hidx];
        lr = rdot[ridx];
    }

    // distribute: lane (g,p) handles memories m = 4k+g
    int ti[8]; float lhv[8], lrv[8];
#pragma unroll
    for (int k = 0; k < 8; ++k) {
        const int m = 4 * k + g;
        ti[k]  = __shfl(tidx, m, 64);
        lhv[k] = __shfl(lh,   m, 64);
        lrv[k] = __shfl(lr,   m, 64);
    }

    // ---- Phase A: 8 tail f4 row-gathers (the only bulk VMEM) ----
    f4 te[8];
#pragma unroll
    for (int k = 0; k < 8; ++k) te[k] = E4[(size_t)ti[k] * 16 + p];

    // ---- Phase B: 16-lane reduces, sigmoid+exp (same float order as before)
    float e[8];
    float se = 0.f;
#pragma unroll
    for (int k = 0; k < 8; ++k) {
        float v = te[k].x * wt.x + te[k].y * wt.y + te[k].z * wt.z + te[k].w * wt.w;
        v += __shfl_xor(v, 1, 64);
        v += __shfl_xor(v, 2, 64);
        v += __shfl_xor(v, 4, 64);
        v += __shfl_xor(v, 8, 64);
        const float logit = v + lhv[k] + lrv[k] + bias;
        const float sig   = 1.f / (1.f + __expf(-logit));
        const float ex    = __expf(sig);
        e[k] = ex;
        se += ex;
    }
    se += __shfl_xor(se, 16, 64);
    se += __shfl_xor(se, 32, 64);
    const float inv = 1.f / se;

    // ---- Phase C: weighted tail sum from registers ----
    f4 acc = {0.f, 0.f, 0.f, 0.f};
#pragma unroll
    for (int k = 0; k < 8; ++k) {
        const float w = e[k] * inv;
        acc.x += w * te[k].x;
        acc.y += w * te[k].y;
        acc.z += w * te[k].z;
        acc.w += w * te[k].w;
    }

    acc.x += __shfl_xor(acc.x, 16, 64);
    acc.x += __shfl_xor(acc.x, 32, 64);
    acc.y += __shfl_xor(acc.y, 16, 64);
    acc.y += __shfl_xor(acc.y, 32, 64);
    acc.z += __shfl_xor(acc.z, 16, 64);
    acc.z += __shfl_xor(acc.z, 32, 64);
    acc.w += __shfl_xor(acc.w, 16, 64);
    acc.w += __shfl_xor(acc.w, 32, 64);
    if (g == 0) ((f4*)accp)[((size_t)i * 2 + h) * 16 + p] = acc;
}

// folded[i] = entity[item_ids[i]] + accp[i][0] + accp[i][1]
__global__ __launch_bounds__(256) void ripple_fold(
    const float* __restrict__ entity_emb,
    const int*   __restrict__ item_ids,
    const float* __restrict__ accp,
    float*       __restrict__ folded)
{
    const int t = blockIdx.x * blockDim.x + threadIdx.x;
    if (t >= N_ITEM * 16) return;
    const int i = t >> 4;
    const int p = t & 15;
    const f4* __restrict__ E4 = (const f4*)entity_emb;
    const f4* __restrict__ A4 = (const f4*)accp;
    const f4 a  = A4[(size_t)i * 32 + p];
    const f4 b  = A4[(size_t)i * 32 + 16 + p];
    const f4 it = E4[(size_t)item_ids[i] * 16 + p];
    f4 r;
    r.x = it.x + a.x + b.x;
    r.y = it.y + a.y + b.y;
    r.z = it.z + a.z + b.z;
    r.w = it.w + a.w + b.w;
    ((f4*)folded)[(size_t)i * 16 + p] = r;
}

// ---------------------------------------------------------------------------
// Stage 2 (TA-slot-minimal): one wave per batch row. The 50 history indices
// are loaded ONCE (one instr, lane j holds index j) and redistributed via
// __shfl. VMEM instrs/wave: 1 idx + 13 row gathers + 1 pair + 1 store = 16
// (was 27).
// ---------------------------------------------------------------------------
__global__ __launch_bounds__(256) void ripple_stage2(
    const float* __restrict__ entity_emb,
    const int*   __restrict__ records_idx,
    const int*   __restrict__ items,
    const float* __restrict__ folded,
    float*       __restrict__ out)
{
    const int wave = (blockIdx.x * blockDim.x + threadIdx.x) >> 6;
    const int lane = threadIdx.x & 63;
    if (wave >= BATCH) return;
    const int b = wave;
    const int g = lane >> 4;
    const int p = lane & 15;

    const f4* __restrict__ A4 = (const f4*)folded;
    const f4* __restrict__ E4 = (const f4*)entity_emb;

    const int rb = b * HIST;
    const int lc = lane < HIST ? lane : (HIST - 1);
    const int idxl = records_idx[rb + lc];     // one instr; lane j<50 holds idx j

    f4 user = {0.f, 0.f, 0.f, 0.f};
#pragma unroll
    for (int k = 0; k < 13; ++k) {
        const int   j  = 4 * k + g;
        const int   js = j < HIST ? j : 0;
        const float w  = j < HIST ? 1.f : 0.f;
        const int  idx = __shfl(idxl, js, 64);
        const f4 r = A4[(size_t)idx * 16 + p];
        user.x += w * r.x;
        user.y += w * r.y;
        user.z += w * r.z;
        user.w += w * r.w;
    }
    user.x += __shfl_xor(user.x, 16, 64);
    user.x += __shfl_xor(user.x, 32, 64);
    user.y += __shfl_xor(user.y, 16, 64);
    user.y += __shfl_xor(user.y, 32, 64);
    user.z += __shfl_xor(user.z, 16, 64);
    user.z += __shfl_xor(user.z, 32, 64);
    user.w += __shfl_xor(user.w, 16, 64);
    user.w += __shfl_xor(user.w, 32, 64);

    const f4 pair = E4[(size_t)items[b] * 16 + p];
    float dot = user.x * pair.x + user.y * pair.y + user.z * pair.z + user.w * pair.w;
    dot += __shfl_xor(dot, 1, 64);
    dot += __shfl_xor(dot, 2, 64);
    dot += __shfl_xor(dot, 4, 64);
    dot += __shfl_xor(dot, 8, 64);
    if (lane == 0) out[b] = 1.f / (1.f + __expf(-dot));
}

extern "C" void kernel_launch(void* const* d_in, const int* in_sizes, int n_in,
                              void* d_out, int out_size, void* d_ws, size_t ws_size,
                              hipStream_t stream) {
    const float* entity_emb   = (const float*)d_in[0];
    const float* relation_emb = (const float*)d_in[1];
    const float* W_w          = (const float*)d_in[2];
    const float* W_b          = (const float*)d_in[3];
    const int*   item_ids     = (const int*)d_in[4];
    const int*   heads        = (const int*)d_in[5];
    const int*   relations    = (const int*)d_in[6];
    const int*   tails        = (const int*)d_in[7];
    const int*   records_idx  = (const int*)d_in[8];
    const int*   items        = (const int*)d_in[9];
    float* out = (float*)d_out;

    float* rdot   = (float*)d_ws;                          // 128 B
    float* hdot   = rdot + N_REL;                          // 2 MB
    float* accp   = hdot + N_ENTITY;                       // 5.12 MB
    float* folded = accp + (size_t)N_ITEM * HOPS * DIM;    // 2.56 MB

    // dots: (N_ENTITY + N_REL) rows, 4 rows/wave, 4 waves/block -> 16 rows/block
    const int rowsD   = N_ENTITY + N_REL;
    const int blocksD = (rowsD + 15) / 16;
    ripple_dots<<<blocksD, 256, 0, stream>>>(entity_emb, relation_emb, W_w, hdot, rdot);

    const int waves1  = HOPS * N_ITEM;          // 20000 waves, 4 per block
    const int blocks1 = (waves1 + 3) / 4;
    ripple_stage1<<<blocks1, 256, 0, stream>>>(W_w, W_b, heads, relations, tails,
                                               entity_emb, hdot, rdot, accp);

    const int blocksF = (N_ITEM * 16 + 255) / 256;
    ripple_fold<<<blocksF, 256, 0, stream>>>(entity_emb, item_ids, accp, folded);

    const int blocks2 = (BATCH + 3) / 4;
    ripple_stage2<<<blocks2, 256, 0, stream>>>(entity_emb, records_idx, items,
                                               folded, out);
}

// Round 3
// 225.521 us; speedup vs baseline: 1.0429x; 1.0413x over previous
//
#include <hip/hip_runtime.h>
#include <math.h>

#define DIM      64
#define N_MEM    32
#define N_ENTITY 500000
#define N_REL    32
#define N_ITEM   10000
#define HOPS     2
#define BATCH    4096
#define HIST     50

typedef float4 f4;

// ---------------------------------------------------------------------------
// Tiny pass: rdot[r] = dot(relation[r], w_r) for 32 relations. ~2us.
// ---------------------------------------------------------------------------
__global__ __launch_bounds__(256) void ripple_rdot(
    const float* __restrict__ relation_emb,
    const float* __restrict__ W_w,
    float* __restrict__ rdot)           // [N_REL]
{
    const int wave = (blockIdx.x * blockDim.x + threadIdx.x) >> 6;
    const int lane = threadIdx.x & 63;
    const int g = lane >> 4;
    const int p = lane & 15;
    const int r = wave * 4 + g;
    if (r >= N_REL) return;
    const f4 wr = ((const f4*)W_w)[16 + p];
    const f4 r4 = ((const f4*)relation_emb)[(size_t)r * 16 + p];
    float vr = r4.x * wr.x + r4.y * wr.y + r4.z * wr.z + r4.w * wr.w;
    vr += __shfl_xor(vr, 1, 64);
    vr += __shfl_xor(vr, 2, 64);
    vr += __shfl_xor(vr, 4, 64);
    vr += __shfl_xor(vr, 8, 64);
    if (p == 0) rdot[r] = vr;
}

// ---------------------------------------------------------------------------
// Stage 1 (fused): ONE wave per item handles BOTH hops plus the item row and
// writes folded[i] directly (hops are independent: logits never read acc).
// Eliminates the fold kernel and the accp round-trip (5MB write + 5MB read).
// Index/rdot loads deduped: one lane per (hop, memory), redistributed via
// __shfl. Head/tail row gathers as in the measured-best R0 structure.
// VMEM instrs/wave: 3 idx + 1 rdot + 1 item + 16 head + 16 tail + 1 store.
// ---------------------------------------------------------------------------
__global__ __launch_bounds__(256) void ripple_stage1(
    const float* __restrict__ W_w,
    const float* __restrict__ W_b,
    const int*   __restrict__ heads,
    const int*   __restrict__ relations,
    const int*   __restrict__ tails,
    const float* __restrict__ entity_emb,
    const float* __restrict__ rdot,
    const int*   __restrict__ item_ids,
    float*       __restrict__ folded)    // [N_ITEM][DIM]
{
    const int wave = (blockIdx.x * blockDim.x + threadIdx.x) >> 6;
    const int lane = threadIdx.x & 63;
    if (wave >= N_ITEM) return;
    const int i = wave;
    const int g = lane >> 4;
    const int p = lane & 15;

    const f4* __restrict__ E4 = (const f4*)entity_emb;
    const f4* __restrict__ W4 = (const f4*)W_w;
    const f4 wh = W4[p];
    const f4 wt = W4[32 + p];
    const float bias = W_b[0];

    // ---- Indices for BOTH hops in one instruction per array:
    // lanes 0..31 -> hop0 memory m=lane; lanes 32..63 -> hop1 memory m=lane-32.
    const int m    = lane & 31;
    const int hsel = lane >> 5;
    const size_t idxoff = (size_t)hsel * ((size_t)N_ITEM * N_MEM)
                        + (size_t)i * N_MEM + m;
    const int   hidx = heads[idxoff];
    const int   ridx = relations[idxoff];
    const int   tidx = tails[idxoff];
    const float lrl  = rdot[ridx];

    const f4 item = E4[(size_t)item_ids[i] * 16 + p];

    f4 accs[2];
#pragma unroll
    for (int h = 0; h < 2; ++h) {
        // distribute: lane (g,p) handles memories m = 4k+g of hop h
        int hi[8], ti[8]; float lrv[8];
#pragma unroll
        for (int k = 0; k < 8; ++k) {
            const int src = h * 32 + 4 * k + g;
            hi[k]  = __shfl(hidx, src, 64);
            ti[k]  = __shfl(tidx, src, 64);
            lrv[k] = __shfl(lrl,  src, 64);
        }

        // 16 f4 row-gathers in flight (head + tail)
        f4 he[8], te[8];
#pragma unroll
        for (int k = 0; k < 8; ++k) he[k] = E4[(size_t)hi[k] * 16 + p];
#pragma unroll
        for (int k = 0; k < 8; ++k) te[k] = E4[(size_t)ti[k] * 16 + p];

        // 16-lane reduces (4 memories in parallel), sigmoid+exp
        float e[8];
        float se = 0.f;
#pragma unroll
        for (int k = 0; k < 8; ++k) {
            float v = he[k].x * wh.x + he[k].y * wh.y + he[k].z * wh.z + he[k].w * wh.w
                    + te[k].x * wt.x + te[k].y * wt.y + te[k].z * wt.z + te[k].w * wt.w;
            v += __shfl_xor(v, 1, 64);
            v += __shfl_xor(v, 2, 64);
            v += __shfl_xor(v, 4, 64);
            v += __shfl_xor(v, 8, 64);
            const float logit = v + lrv[k] + bias;
            const float sig   = 1.f / (1.f + __expf(-logit));
            const float ex    = __expf(sig);
            e[k] = ex;
            se += ex;
        }
        se += __shfl_xor(se, 16, 64);
        se += __shfl_xor(se, 32, 64);
        const float inv = 1.f / se;

        // weighted tail sum from registers
        f4 acc = {0.f, 0.f, 0.f, 0.f};
#pragma unroll
        for (int k = 0; k < 8; ++k) {
            const float w = e[k] * inv;
            acc.x += w * te[k].x;
            acc.y += w * te[k].y;
            acc.z += w * te[k].z;
            acc.w += w * te[k].w;
        }
        acc.x += __shfl_xor(acc.x, 16, 64);
        acc.x += __shfl_xor(acc.x, 32, 64);
        acc.y += __shfl_xor(acc.y, 16, 64);
        acc.y += __shfl_xor(acc.y, 32, 64);
        acc.z += __shfl_xor(acc.z, 16, 64);
        acc.z += __shfl_xor(acc.z, 32, 64);
        acc.w += __shfl_xor(acc.w, 16, 64);
        acc.w += __shfl_xor(acc.w, 32, 64);
        accs[h] = acc;
    }

    if (g == 0) {
        f4 r;
        r.x = item.x + accs[0].x + accs[1].x;   // (item + hop0) + hop1 order
        r.y = item.y + accs[0].y + accs[1].y;
        r.z = item.z + accs[0].z + accs[1].z;
        r.w = item.w + accs[0].w + accs[1].w;
        ((f4*)folded)[(size_t)i * 16 + p] = r;
    }
}

// ---------------------------------------------------------------------------
// Stage 2: one wave per batch row; 50 history indices loaded once (one instr)
// and redistributed via __shfl.
// ---------------------------------------------------------------------------
__global__ __launch_bounds__(256) void ripple_stage2(
    const float* __restrict__ entity_emb,
    const int*   __restrict__ records_idx,
    const int*   __restrict__ items,
    const float* __restrict__ folded,
    float*       __restrict__ out)
{
    const int wave = (blockIdx.x * blockDim.x + threadIdx.x) >> 6;
    const int lane = threadIdx.x & 63;
    if (wave >= BATCH) return;
    const int b = wave;
    const int g = lane >> 4;
    const int p = lane & 15;

    const f4* __restrict__ A4 = (const f4*)folded;
    const f4* __restrict__ E4 = (const f4*)entity_emb;

    const int rb = b * HIST;
    const int lc = lane < HIST ? lane : (HIST - 1);
    const int idxl = records_idx[rb + lc];     // lane j<50 holds index j

    f4 user = {0.f, 0.f, 0.f, 0.f};
#pragma unroll
    for (int k = 0; k < 13; ++k) {
        const int   j  = 4 * k + g;
        const int   js = j < HIST ? j : 0;
        const float w  = j < HIST ? 1.f : 0.f;
        const int  idx = __shfl(idxl, js, 64);
        const f4 r = A4[(size_t)idx * 16 + p];
        user.x += w * r.x;
        user.y += w * r.y;
        user.z += w * r.z;
        user.w += w * r.w;
    }
    user.x += __shfl_xor(user.x, 16, 64);
    user.x += __shfl_xor(user.x, 32, 64);
    user.y += __shfl_xor(user.y, 16, 64);
    user.y += __shfl_xor(user.y, 32, 64);
    user.z += __shfl_xor(user.z, 16, 64);
    user.z += __shfl_xor(user.z, 32, 64);
    user.w += __shfl_xor(user.w, 16, 64);
    user.w += __shfl_xor(user.w, 32, 64);

    const f4 pair = E4[(size_t)items[b] * 16 + p];
    float dot = user.x * pair.x + user.y * pair.y + user.z * pair.z + user.w * pair.w;
    dot += __shfl_xor(dot, 1, 64);
    dot += __shfl_xor(dot, 2, 64);
    dot += __shfl_xor(dot, 4, 64);
    dot += __shfl_xor(dot, 8, 64);
    if (lane == 0) out[b] = 1.f / (1.f + __expf(-dot));
}

extern "C" void kernel_launch(void* const* d_in, const int* in_sizes, int n_in,
                              void* d_out, int out_size, void* d_ws, size_t ws_size,
                              hipStream_t stream) {
    const float* entity_emb   = (const float*)d_in[0];
    const float* relation_emb = (const float*)d_in[1];
    const float* W_w          = (const float*)d_in[2];
    const float* W_b          = (const float*)d_in[3];
    const int*   item_ids     = (const int*)d_in[4];
    const int*   heads        = (const int*)d_in[5];
    const int*   relations    = (const int*)d_in[6];
    const int*   tails        = (const int*)d_in[7];
    const int*   records_idx  = (const int*)d_in[8];
    const int*   items        = (const int*)d_in[9];
    float* out = (float*)d_out;

    float* rdot   = (float*)d_ws;                          // 128 B
    float* folded = rdot + N_REL;                          // 2.56 MB

    ripple_rdot<<<2, 256, 0, stream>>>(relation_emb, W_w, rdot);

    const int blocks1 = (N_ITEM + 3) / 4;      // one wave per item, 4 waves/block
    ripple_stage1<<<blocks1, 256, 0, stream>>>(W_w, W_b, heads, relations, tails,
                                               entity_emb, rdot, item_ids, folded);

    const int blocks2 = (BATCH + 3) / 4;
    ripple_stage2<<<blocks2, 256, 0, stream>>>(entity_emb, records_idx, items,
                                               folded, out);
}